// Round 3
// baseline (7405.183 us; speedup 1.0000x reference)
//
#include <hip/hip_runtime.h>
#include <cstdint>

#define SEQ   2048
#define BATCH 128
#define IN    64
#define HID   256
#define OUTD  64

#define T     512
#define NHH   32   // W_hh 8-dim chunks per row (256 dims): slots 0..15 own half, 16..31 peer half
#define NIH   8    // W_ih 8-dim chunks per row (64 dims)

// ---- ws layout in dwords ----
#define OFF_WHH  0
#define SZ_WHH   (2*NHH*512*4)           // 131072 dw
#define OFF_WIH  (OFF_WHH+SZ_WHH)        // 131072
#define SZ_WIH   (2*NIH*512*4)           // 32768
#define OFF_WOUT (OFF_WIH+SZ_WIH)        // 163840
#define SZ_WOUT  8192                    // 64*256 f16
#define OFF_EXCH (OFF_WOUT+SZ_WOUT)      // 172032
#define SZ_EXCH  (2*BATCH*2*64)          // 32768 dw: [block(256)][parity(2)][128 f16]
#define OFF_FLAG (OFF_EXCH+SZ_EXCH)      // 204800
#define SZ_FLAG  (2*BATCH*16)            // 4096 dw: one flag per block, 64B stride
#define TOTAL_DW (OFF_FLAG+SZ_FLAG)      // 208896 dw = 835 KB

typedef _Float16 f16x2 __attribute__((ext_vector_type(2)));

__device__ __forceinline__ float fexp2(float v) { return __builtin_amdgcn_exp2f(v); }
__device__ __forceinline__ float frcp(float v)  { return __builtin_amdgcn_rcpf(v); }
__device__ __forceinline__ float fsig(float v)  { return frcp(1.0f + fexp2(v * -1.44269504088896f)); }
__device__ __forceinline__ float ftanh_(float v){ return 1.0f - 2.0f * frcp(1.0f + fexp2(v * 2.88539008177793f)); }

__device__ __forceinline__ unsigned int pack2d(float a, float b) {
  unsigned short lo = __builtin_bit_cast(unsigned short, (_Float16)a);
  unsigned short hi = __builtin_bit_cast(unsigned short, (_Float16)b);
  return (unsigned int)lo | ((unsigned int)hi << 16);
}

__device__ __forceinline__ float dot2f(unsigned int w, unsigned int h, float acc) {
#if __has_builtin(__builtin_amdgcn_fdot2)
  return __builtin_amdgcn_fdot2(__builtin_bit_cast(f16x2, w), __builtin_bit_cast(f16x2, h), acc, false);
#else
  f16x2 a = __builtin_bit_cast(f16x2, w), b = __builtin_bit_cast(f16x2, h);
  return acc + (float)a.x * (float)b.x + (float)a.y * (float)b.y;
#endif
}

__device__ __forceinline__ void mac8(uint4 w, uint4 h, float& acc) {
  acc = dot2f(w.x, h.x, acc);
  acc = dot2f(w.y, h.y, acc);
  acc = dot2f(w.z, h.z, acc);
  acc = dot2f(w.w, h.w, acc);
}

// Pin a loaded value into VGPRs: asm-defined values cannot be rematerialized
// as loads, so aliasing with the exchange stores can't sink them into the loop.
#define PIN4(v) asm volatile("" : "+v"((v).x), "+v"((v).y), "+v"((v).z), "+v"((v).w))

// ---------------- prep: fp32 weights -> packed f16 layouts; zero sync flags ----------------
__global__ void prep_weights(const float* __restrict__ Whh, const float* __restrict__ Wih,
                             const float* __restrict__ Wout, unsigned int* __restrict__ ws) {
  int tid = blockIdx.x * 256 + threadIdx.x;
  if (tid >= TOTAL_DW) return;
  if (tid >= OFF_FLAG) { ws[tid] = 0u; return; }   // reset flags every launch (graph-replay safe)
  if (tid >= OFF_EXCH) return;                     // exchange data needs no init (flag-gated)
  unsigned int val;
  if (tid < OFF_WIH) {                             // W_hh: [half][slot][t][q]
    int q = tid & 3, t = (tid >> 2) & 511, rest = tid >> 11;
    int slot = rest & 31, half = rest >> 5;
    int c = (half*16 + slot) & 31;                 // slot 0..15 -> own-half h chunks, 16..31 -> peer
    int row = (t >> 7)*256 + half*128 + (t & 127); // gate (t>>7), unit half*128+(t&127)
    const float* p = Whh + (size_t)row*HID + 8*c + 2*q;
    val = pack2d(p[0], p[1]);
  } else if (tid < OFF_WOUT) {                     // W_ih: [half][j][t][q]
    int r = tid - OFF_WIH;
    int q = r & 3, t = (r >> 2) & 511, rest = r >> 11;
    int j = rest & 7, half = rest >> 3;
    int row = (t >> 7)*256 + half*128 + (t & 127);
    const float* p = Wih + (size_t)row*IN + 8*j + 2*q;
    val = pack2d(p[0], p[1]);
  } else {                                         // W_out linear f16
    int r = tid - OFF_WOUT;
    const float* p = Wout + 2*r;
    val = pack2d(p[0], p[1]);
  }
  ws[tid] = val;
}

// ---------------- main: TWO blocks per batch element (grid = 256) ----------------
// Block pair (bid, bid^128): same XCD under round-robin dispatch (128 % 8 == 0).
// half = bid>>7 owns hidden units [half*128, half*128+128) FULLY (all 4 gates):
// thread t computes gate row (t>>7)*256 + half*128 + (t&127). The h,c update is
// block-local; only 128 f16 h-values are exchanged per step (vs 2KB of lins before).
// Weights (168 dw/thread) are PIN4'd into VGPRs -> zero per-step weight traffic.
// Peer-h L3 round trip is hidden under the own-half + W_ih dot products; readout
// is deferred one step (out[s-1] while h_s is fresh).
__global__ __launch_bounds__(512, 2) void lstm_main(
    const float* __restrict__ x, const float* __restrict__ h0, const float* __restrict__ c0,
    const float* __restrict__ bias, const float* __restrict__ b_out,
    unsigned int* __restrict__ ws, float* __restrict__ out)
{
  const int bid = blockIdx.x;
  const int b = bid & 127, half = bid >> 7, t = threadIdx.x;
  const int base_own = half*128, base_peer = 128 - half*128;

  __shared__ __align__(16) float lin_sh[T];            // 2 KiB
  __shared__ __align__(16) unsigned short hs[HID];     // h_s as f16 (own half live, peer merged per step)
  __shared__ __align__(16) unsigned short xs[IN];      // x_s as f16

  const unsigned int* WhhS = ws + OFF_WHH;
  const unsigned int* WihS = ws + OFF_WIH;
  const unsigned short* WoutS = (const unsigned short*)(ws + OFF_WOUT);
  unsigned short* E = (unsigned short*)(ws + OFF_EXCH);
  unsigned short* myE = E + (size_t)bid * 256;                 // [parity(2)][128]
  const unsigned short* peerE = E + (size_t)(bid ^ 128) * 256;
  unsigned int* flagv  = ws + OFF_FLAG;
  unsigned int* myflag = flagv + (size_t)bid * 16;
  unsigned int* pflag  = flagv + (size_t)(bid ^ 128) * 16;

  // ---- load + pin persistent register weights ----
  uint4 whh[NHH];
  #pragma unroll
  for (int j = 0; j < NHH; ++j) {
    whh[j] = *(const uint4*)(WhhS + ((size_t)(half*NHH + j)*512 + t)*4);
    PIN4(whh[j]);
  }
  uint4 wih[NIH];
  #pragma unroll
  for (int j = 0; j < NIH; ++j) {
    wih[j] = *(const uint4*)(WihS + ((size_t)(half*NIH + j)*512 + t)*4);
    PIN4(wih[j]);
  }
  const int oglob = half*32 + (t >> 4), seg = t & 15;  // 32 outputs/block, 16 lanes x 16 dims
  uint4 wo[2];
  #pragma unroll
  for (int q = 0; q < 2; ++q) {
    wo[q] = *(const uint4*)(WoutS + (size_t)oglob*256 + seg*16 + q*8);
    PIN4(wo[q]);
  }

  // ---- state init ----
  float c = 0.0f;
  if (t < 128) c = c0[(size_t)b*HID + base_own + t];
  if (t < 256) {
    hs[t] = (unsigned short)(pack2d(h0[(size_t)b*HID + t], 0.0f) & 0xffffu);
  } else if (t < 288) {
    int i = t - 256;
    float2 xx = *(const float2*)(x + (size_t)b*IN + 2*i);   // x at s=0
    ((unsigned int*)xs)[i] = pack2d(xx.x, xx.y);
  }
  const float bz = bias[(t >> 7)*256 + half*128 + (t & 127)];
  const float bo = b_out[oglob];
  __syncthreads();

  for (int s = 0; s < SEQ; ++s) {
    // A: dots over OWN half of h_s + full W_ih·x_s (peer fetch overlaps this)
    float la = bz, lb = 0.0f;
    #pragma unroll
    for (int k = 0; k < 16; ++k) {
      uint4 hv = *(const uint4*)(hs + base_own + 8*k);
      if (k & 1) mac8(whh[k], hv, lb); else mac8(whh[k], hv, la);
    }
    #pragma unroll
    for (int j = 0; j < NIH; ++j) {
      uint4 xv = *(const uint4*)(xs + 8*j);
      if (j & 1) mac8(wih[j], xv, lb); else mac8(wih[j], xv, la);
    }

    // B: x_{s+1} prefetch + peer h_s fetch into LDS
    float2 xn = make_float2(0.0f, 0.0f);
    if (t >= 256 && t < 288) {
      int sn = (s + 1 < SEQ) ? s + 1 : s;
      xn = *(const float2*)(x + ((size_t)sn*BATCH + b)*IN + 2*(t - 256));
    }
    if (s > 0 && t < 64) {
      while (__hip_atomic_load(pflag, __ATOMIC_RELAXED, __HIP_MEMORY_SCOPE_AGENT) < (unsigned)s) {}
      __asm__ volatile("" ::: "memory");
      unsigned int u = __hip_atomic_load((const unsigned int*)peerE + (s & 1)*64 + t,
                                         __ATOMIC_RELAXED, __HIP_MEMORY_SCOPE_AGENT);
      ((unsigned int*)(hs + base_peer))[t] = u;
    }
    __syncthreads();  // (C) peer half of h_s in LDS

    // D: dots over PEER half of h_s
    #pragma unroll
    for (int k = 0; k < 16; ++k) {
      uint4 hv = *(const uint4*)(hs + base_peer + 8*k);
      if (k & 1) mac8(whh[16 + k], hv, lb); else mac8(whh[16 + k], hv, la);
    }
    lin_sh[t] = la + lb;

    // E: deferred readout out[s-1] from full h_s (off the recurrence critical path)
    float acc = 0.0f;
    #pragma unroll
    for (int q = 0; q < 2; ++q) {
      uint4 hv = *(const uint4*)(hs + seg*16 + 8*q);
      mac8(wo[q], hv, acc);
    }
    acc += __shfl_xor(acc, 1);
    acc += __shfl_xor(acc, 2);
    acc += __shfl_xor(acc, 4);
    acc += __shfl_xor(acc, 8);
    if (s > 0 && seg == 0) out[((size_t)(s - 1)*BATCH + b)*OUTD + oglob] = acc + bo;

    __syncthreads();  // (F) lin_sh complete; all hs reads done

    // G: block-local gates -> h_{s+1}, c_{s+1} for own 128 units; publish h to peer
    if (t < 128) {
      float li  = lin_sh[t];
      float lf  = lin_sh[128 + t];
      float lg  = lin_sh[256 + t];
      float lo_ = lin_sh[384 + t];
      float ig = fsig(li), fg = fsig(lf), gg = ftanh_(lg), og = fsig(lo_);
      c = fg*c + ig*gg;
      float hn = og*ftanh_(c);
      unsigned short hp = (unsigned short)(pack2d(hn, 0.0f) & 0xffffu);
      hs[base_own + t] = hp;
      __hip_atomic_store(myE + ((s + 1) & 1)*128 + t, hp,
                         __ATOMIC_RELAXED, __HIP_MEMORY_SCOPE_AGENT);
    } else if (t >= 256 && t < 288) {
      ((unsigned int*)xs)[t - 256] = pack2d(xn.x, xn.y);
    }
    __syncthreads();  // (H) hs/xs updated; publish stores drained (vmcnt(0) before s_barrier)

    if (t == 0)
      __hip_atomic_store(myflag, (unsigned)(s + 1),
                         __ATOMIC_RELAXED, __HIP_MEMORY_SCOPE_AGENT);
  }

  // epilogue: merge peer h_SEQ and emit out[SEQ-1]
  if (t < 64) {
    while (__hip_atomic_load(pflag, __ATOMIC_RELAXED, __HIP_MEMORY_SCOPE_AGENT) < (unsigned)SEQ) {}
    __asm__ volatile("" ::: "memory");
    unsigned int u = __hip_atomic_load((const unsigned int*)peerE + (SEQ & 1)*64 + t,
                                       __ATOMIC_RELAXED, __HIP_MEMORY_SCOPE_AGENT);
    ((unsigned int*)(hs + base_peer))[t] = u;
  }
  __syncthreads();
  float acc = 0.0f;
  #pragma unroll
  for (int q = 0; q < 2; ++q) {
    uint4 hv = *(const uint4*)(hs + seg*16 + 8*q);
    mac8(wo[q], hv, acc);
  }
  acc += __shfl_xor(acc, 1);
  acc += __shfl_xor(acc, 2);
  acc += __shfl_xor(acc, 4);
  acc += __shfl_xor(acc, 8);
  if (seg == 0) out[((size_t)(SEQ - 1)*BATCH + b)*OUTD + oglob] = acc + bo;
}

extern "C" void kernel_launch(void* const* d_in, const int* in_sizes, int n_in,
                              void* d_out, int out_size, void* d_ws, size_t ws_size,
                              hipStream_t stream) {
  const float* x     = (const float*)d_in[0];
  const float* h0    = (const float*)d_in[1];
  const float* c0    = (const float*)d_in[2];
  const float* W_ih  = (const float*)d_in[3];
  const float* W_hh  = (const float*)d_in[4];
  const float* bias  = (const float*)d_in[5];
  const float* W_out = (const float*)d_in[6];
  const float* b_out = (const float*)d_in[7];
  float* out = (float*)d_out;
  unsigned int* ws = (unsigned int*)d_ws;

  hipLaunchKernelGGL(prep_weights, dim3((TOTAL_DW + 255)/256), dim3(256), 0, stream,
                     W_hh, W_ih, W_out, ws);
  hipLaunchKernelGGL(lstm_main, dim3(2*BATCH), dim3(T), 0, stream,
                     x, h0, c0, bias, b_out, ws, out);
}